// Round 1
// 1241.321 us; speedup vs baseline: 1.1766x; 1.1766x over previous
//
#include <hip/hip_runtime.h>

typedef unsigned short u16;
typedef __attribute__((ext_vector_type(4))) float floatx4;
typedef __attribute__((ext_vector_type(8))) short shortx8;

#define Bb 2
#define Tt 2048
#define Ee 1024
#define Hh 16
#define Dd 64
#define Vv 32000
#define Mm 4096  // B*T
#define NBLK_LM 250  // Vv/128

// ---------- helpers ----------
__device__ __forceinline__ u16 f2b(float x) {  // f32 -> bf16 RNE
  union { float f; unsigned u; } v; v.f = x;
  unsigned r = v.u + 0x7fffu + ((v.u >> 16) & 1u);
  return (u16)(r >> 16);
}

__device__ __forceinline__ void gload_lds16(const void* g, void* l) {
  __builtin_amdgcn_global_load_lds((__attribute__((address_space(1))) const void*)g,
                                   (__attribute__((address_space(3))) void*)l, 16, 0, 0);
}

// ---------- embed: x_bf16[m][e] = bf16(tok_emb[idx[m]][e] + pos_emb[t][e]) ----------
__global__ __launch_bounds__(256) void embed_kernel(const int* __restrict__ idx,
                                                    const float* __restrict__ tok,
                                                    const float* __restrict__ pos,
                                                    u16* __restrict__ xout) {
  int i = blockIdx.x * 256 + threadIdx.x;       // 4096*128 total, 8 elems each
  int m = i >> 7, ch = i & 127;
  int t = m & (Tt - 1);
  int row = idx[m];
  const float4* ta = (const float4*)(tok + (size_t)row * Ee + ch * 8);
  const float4* pa = (const float4*)(pos + (size_t)t * Ee + ch * 8);
  float4 a0 = ta[0], a1 = ta[1], p0 = pa[0], p1 = pa[1];
  u16 r[8];
  r[0] = f2b(a0.x + p0.x); r[1] = f2b(a0.y + p0.y);
  r[2] = f2b(a0.z + p0.z); r[3] = f2b(a0.w + p0.w);
  r[4] = f2b(a1.x + p1.x); r[5] = f2b(a1.y + p1.y);
  r[6] = f2b(a1.z + p1.z); r[7] = f2b(a1.w + p1.w);
  *(uint4*)&xout[(size_t)m * Ee + ch * 8] = *(uint4*)r;
}

// ---------- wq/wk/wv [H][E][D] f32 -> wqkvT [3][H][D][E] bf16 ----------
__global__ __launch_bounds__(256) void prep_qkv(const float* __restrict__ wq,
                                                const float* __restrict__ wk,
                                                const float* __restrict__ wv,
                                                u16* __restrict__ outT) {
  int o = blockIdx.x * 256 + threadIdx.x;       // 3*16*64*1024 = 3*2^20
  int e = o & 1023, d = (o >> 10) & 63, h = (o >> 16) & 15, s = o >> 20;
  const float* w = (s == 0) ? wq : ((s == 1) ? wk : wv);
  outT[o] = f2b(w[((size_t)(h * Ee + e)) * Dd + d]);
}

// ---------- tiled transpose: in f32 [R][C] -> out bf16 [C][R] ----------
// NT loads: weight matrices are read exactly once here; don't evict useful cache.
__global__ __launch_bounds__(256) void transpose_f32_bf16(const float* __restrict__ in,
                                                          u16* __restrict__ out,
                                                          int R, int C) {
  __shared__ float tile[64][65];
  int c0 = blockIdx.x * 64, r0 = blockIdx.y * 64;
  int tid = threadIdx.x;
  for (int i = tid; i < 4096; i += 256) {
    int rr = i >> 6, cc = i & 63;
    tile[rr][cc] = __builtin_nontemporal_load(&in[(size_t)(r0 + rr) * C + c0 + cc]);
  }
  __syncthreads();
  for (int i = tid; i < 4096; i += 256) {
    int cc = i >> 6, rr = i & 63;
    out[(size_t)(c0 + cc) * R + r0 + rr] = f2b(tile[rr][cc]);
  }
}

// ---------- MFMA GEMM: C[M,N] = A[M,K]bf16 * Bt[N,K]bf16^T ----------
// EPI 0: f32 out (nontemporal) + per-(row,nblock) logsumexp partials
// EPI 1: bf16(relu(acc+bias))   EPI 2: QKV scatter (q scaled by E^-0.5)
// Grid requirement: gridDim.y == 32 and (gridDim.x*gridDim.y) % 8 == 0 (all call sites).
template <int EPI>
__global__ __launch_bounds__(256)
void gemm_bt(const u16* __restrict__ A, const u16* __restrict__ Bt,
             int M, int N, int K,
             float* __restrict__ Cf, u16* __restrict__ Cb,
             const float* __restrict__ bias,
             u16* __restrict__ q_out, u16* __restrict__ k_out, u16* __restrict__ v_out,
             float2* __restrict__ stats) {
  __shared__ u16 sA[128 * 32];
  __shared__ u16 sB[128 * 32];
  const int tid = threadIdx.x, lane = tid & 63, w = tid >> 6;
  const int quad = lane >> 4, l16 = lane & 15;
  // Bijective XCD swizzle (T1): XCD k owns a 4-row M-strip; within the strip,
  // blocks go B-panel-major (4 consecutive blocks share one Bt panel -> L2 hit).
  const int wg = blockIdx.y * gridDim.x + blockIdx.x;
  const int xcd = wg & 7, loc = wg >> 3;
  const int bxs = loc >> 2, bys = (xcd << 2) + (loc & 3);
  const int m0 = bys * 128, n0 = bxs * 128;
  const int wr = w >> 1, wc = w & 1;
  const int r4 = lane >> 2, c4 = lane & 3;

  floatx4 acc[4][4];
  floatx4 zz = {0.f, 0.f, 0.f, 0.f};
#pragma unroll
  for (int i = 0; i < 4; ++i)
#pragma unroll
    for (int j = 0; j < 4; ++j) acc[i][j] = zz;

  const int kiters = K >> 5;
  for (int kt = 0; kt < kiters; ++kt) {
    __syncthreads();
#pragma unroll
    for (int j = 0; j < 2; ++j) {
      const int rowblk = (w * 2 + j) * 16;
      gload_lds16(A + (size_t)(m0 + rowblk + r4) * K + (kt << 5) + c4 * 8, &sA[rowblk * 32]);
      gload_lds16(Bt + (size_t)(n0 + rowblk + r4) * K + (kt << 5) + c4 * 8, &sB[rowblk * 32]);
    }
    __syncthreads();
    shortx8 af[4], bfr[4];
#pragma unroll
    for (int mi = 0; mi < 4; ++mi)
      af[mi] = *(const shortx8*)&sA[(wr * 64 + mi * 16 + l16) * 32 + quad * 8];
#pragma unroll
    for (int ni = 0; ni < 4; ++ni)
      bfr[ni] = *(const shortx8*)&sB[(wc * 64 + ni * 16 + l16) * 32 + quad * 8];
#pragma unroll
    for (int mi = 0; mi < 4; ++mi)
#pragma unroll
      for (int ni = 0; ni < 4; ++ni)
        acc[mi][ni] = __builtin_amdgcn_mfma_f32_16x16x32_bf16(af[mi], bfr[ni], acc[mi][ni], 0, 0, 0);
  }

  if (EPI == 0) {
    // all waves done reading sA/sB before we reuse the LDS for stat exchange
    __syncthreads();
    float* sm = (float*)sA;    // [128][2] row-local max per wc half
    float* ss = (float*)sB;    // [128][2] row-local sumexp per wc half
#pragma unroll
    for (int mi = 0; mi < 4; ++mi) {
#pragma unroll
      for (int r = 0; r < 4; ++r) {
        const int rl = wr * 64 + mi * 16 + quad * 4 + r;
        const int row = m0 + rl;
        float v[4];
#pragma unroll
        for (int ni = 0; ni < 4; ++ni) {
          v[ni] = acc[mi][ni][r];
          const int col = n0 + wc * 64 + ni * 16 + l16;
          __builtin_nontemporal_store(v[ni], &Cf[(size_t)row * N + col]);
        }
        // per-row (64-col half) max + sumexp across the 16 l16 lanes of this quad
        float rmax = fmaxf(fmaxf(v[0], v[1]), fmaxf(v[2], v[3]));
#pragma unroll
        for (int off = 8; off >= 1; off >>= 1) rmax = fmaxf(rmax, __shfl_xor(rmax, off));
        float se = __expf(v[0] - rmax) + __expf(v[1] - rmax) +
                   __expf(v[2] - rmax) + __expf(v[3] - rmax);
#pragma unroll
        for (int off = 8; off >= 1; off >>= 1) se += __shfl_xor(se, off);
        if (l16 == 0) { sm[rl * 2 + wc] = rmax; ss[rl * 2 + wc] = se; }
      }
    }
    __syncthreads();
    if (tid < 128) {
      float m1 = sm[tid * 2], m2 = sm[tid * 2 + 1];
      float s1 = ss[tid * 2], s2 = ss[tid * 2 + 1];
      float Mx = fmaxf(m1, m2);
      float2 st;
      st.x = Mx;
      st.y = s1 * __expf(m1 - Mx) + s2 * __expf(m2 - Mx);
      stats[(size_t)bxs * M + m0 + tid] = st;   // layout [nblock][row] (coalesced write)
    }
    return;
  }

#pragma unroll
  for (int mi = 0; mi < 4; ++mi) {
#pragma unroll
    for (int r = 0; r < 4; ++r) {
      const int row = m0 + wr * 64 + mi * 16 + quad * 4 + r;
#pragma unroll
      for (int ni = 0; ni < 4; ++ni) {
        const int col = n0 + wc * 64 + ni * 16 + l16;
        float v = acc[mi][ni][r];
        if (EPI == 1) {
          v += bias[col];
          v = v > 0.f ? v : 0.f;
          Cb[(size_t)row * N + col] = f2b(v);
        } else {
          int s = col >> 10, hh = (col >> 6) & 15, d = col & 63;
          int b = row >> 11, t = row & (Tt - 1);
          if (s == 0)
            q_out[(((size_t)(b * Hh + hh)) * Tt + t) * Dd + d] = f2b(v * 0.03125f);  // E^-0.5
          else if (s == 1)
            k_out[(((size_t)(b * Hh + hh)) * Tt + t) * Dd + d] = f2b(v);
          else
            v_out[(((size_t)(b * Hh + hh)) * Dd + d) * Tt + t] = f2b(v);
        }
      }
    }
  }
}

// ---------- flash attention: q[b,h,t,d], k[b,h,t,d], vT[b,h,d,t] -> out[b,t,h*64+d] bf16 ----------
__global__ __launch_bounds__(256) void attn_kernel(const u16* __restrict__ qg,
                                                   const u16* __restrict__ kg,
                                                   const u16* __restrict__ vg,
                                                   u16* __restrict__ outg) {
  const int qt = blockIdx.x, h = blockIdx.y, b = blockIdx.z;
  const int tid = threadIdx.x, lane = tid & 63, w = tid >> 6;
  const int quad = lane >> 4, l16 = lane & 15;
  __shared__ u16 sQ[64 * 64], sK[64 * 64], sV[64 * 64];
  __shared__ u16 sP[4][1024];
  const size_t bh = (size_t)b * Hh + h;
  const u16* qb = qg + bh * (Tt * Dd);
  const u16* kb = kg + bh * (Tt * Dd);
  const u16* vb = vg + bh * (Dd * Tt);
  const int q0 = qt * 64;

  for (int i = tid; i < 512; i += 256) {
    int row = i >> 3, ch = i & 7;
    *(uint4*)&sQ[row * 64 + ch * 8] = *(const uint4*)&qb[(size_t)(q0 + row) * Dd + ch * 8];
  }
  __syncthreads();
  shortx8 aq0 = *(const shortx8*)&sQ[(w * 16 + l16) * 64 + quad * 8];
  shortx8 aq1 = *(const shortx8*)&sQ[(w * 16 + l16) * 64 + 32 + quad * 8];

  floatx4 zz = {0.f, 0.f, 0.f, 0.f};
  floatx4 oacc[4];
  float mrow[4], lrow[4];
#pragma unroll
  for (int i = 0; i < 4; ++i) { oacc[i] = zz; mrow[i] = -__builtin_inff(); lrow[i] = 0.f; }

  for (int kt = 0; kt <= qt; ++kt) {
    const int k0 = kt * 64;
    __syncthreads();
    for (int i = tid; i < 512; i += 256) {
      int row = i >> 3, ch = i & 7;
      *(uint4*)&sK[row * 64 + ch * 8] = *(const uint4*)&kb[(size_t)(k0 + row) * Dd + ch * 8];
      *(uint4*)&sV[row * 64 + ch * 8] = *(const uint4*)&vb[(size_t)row * Tt + k0 + ch * 8];
    }
    __syncthreads();
    floatx4 s4[4] = {zz, zz, zz, zz};
#pragma unroll
    for (int ni = 0; ni < 4; ++ni) {
      shortx8 bk0 = *(const shortx8*)&sK[(ni * 16 + l16) * 64 + quad * 8];
      shortx8 bk1 = *(const shortx8*)&sK[(ni * 16 + l16) * 64 + 32 + quad * 8];
      s4[ni] = __builtin_amdgcn_mfma_f32_16x16x32_bf16(aq0, bk0, s4[ni], 0, 0, 0);
      s4[ni] = __builtin_amdgcn_mfma_f32_16x16x32_bf16(aq1, bk1, s4[ni], 0, 0, 0);
    }
    if (kt == qt) {
#pragma unroll
      for (int ni = 0; ni < 4; ++ni)
#pragma unroll
        for (int r = 0; r < 4; ++r) {
          int kloc = ni * 16 + l16, qloc = w * 16 + quad * 4 + r;
          if (kloc > qloc) s4[ni][r] = -__builtin_inff();
        }
    }
#pragma unroll
    for (int r = 0; r < 4; ++r) {
      float rm = fmaxf(fmaxf(s4[0][r], s4[1][r]), fmaxf(s4[2][r], s4[3][r]));
#pragma unroll
      for (int off = 8; off >= 1; off >>= 1) rm = fmaxf(rm, __shfl_xor(rm, off));
      float mnew = fmaxf(mrow[r], rm);
      float alpha = __expf(mrow[r] - mnew);
      float p[4], rsum = 0.f;
#pragma unroll
      for (int ni = 0; ni < 4; ++ni) { p[ni] = __expf(s4[ni][r] - mnew); rsum += p[ni]; }
#pragma unroll
      for (int off = 8; off >= 1; off >>= 1) rsum += __shfl_xor(rsum, off);
      lrow[r] = lrow[r] * alpha + rsum;
      mrow[r] = mnew;
#pragma unroll
      for (int di = 0; di < 4; ++di) oacc[di][r] *= alpha;
#pragma unroll
      for (int ni = 0; ni < 4; ++ni) sP[w][(quad * 4 + r) * 64 + ni * 16 + l16] = f2b(p[ni]);
    }
    __syncthreads();
    shortx8 ap0 = *(const shortx8*)&sP[w][l16 * 64 + quad * 8];
    shortx8 ap1 = *(const shortx8*)&sP[w][l16 * 64 + 32 + quad * 8];
#pragma unroll
    for (int di = 0; di < 4; ++di) {
      shortx8 bv0 = *(const shortx8*)&sV[(di * 16 + l16) * 64 + quad * 8];
      shortx8 bv1 = *(const shortx8*)&sV[(di * 16 + l16) * 64 + 32 + quad * 8];
      oacc[di] = __builtin_amdgcn_mfma_f32_16x16x32_bf16(ap0, bv0, oacc[di], 0, 0, 0);
      oacc[di] = __builtin_amdgcn_mfma_f32_16x16x32_bf16(ap1, bv1, oacc[di], 0, 0, 0);
    }
  }
#pragma unroll
  for (int di = 0; di < 4; ++di)
#pragma unroll
    for (int r = 0; r < 4; ++r) {
      int grow = b * Tt + q0 + w * 16 + quad * 4 + r;
      int col = h * Dd + di * 16 + l16;
      outg[(size_t)grow * Ee + col] = f2b(oacc[di][r] / lrow[r]);
    }
}

// ---------- per-row NLL from GEMM-fused partials ----------
__global__ __launch_bounds__(256) void loss_row2(const float2* __restrict__ stats,
                                                 const float* __restrict__ logits,
                                                 const int* __restrict__ targets,
                                                 float* __restrict__ nll) {
  const int m = blockIdx.x;
  const int tid = threadIdx.x;
  float mx = -__builtin_inff(), sm = 0.f;
  if (tid < NBLK_LM) {
    float2 p = stats[(size_t)tid * Mm + m];
    mx = p.x; sm = p.y;
  }
  __shared__ float red_m[256], red_s[256];
  red_m[tid] = mx; red_s[tid] = sm;
  __syncthreads();
  for (int s = 128; s > 0; s >>= 1) {
    if (tid < s) {
      float m1 = red_m[tid], s1 = red_s[tid];
      float m2 = red_m[tid + s], s2 = red_s[tid + s];
      float M = fmaxf(m1, m2);
      red_s[tid] = s1 * __expf(m1 - M) + s2 * __expf(m2 - M);
      red_m[tid] = M;
    }
    __syncthreads();
  }
  if (tid == 0)
    nll[m] = logf(red_s[0]) + red_m[0] - logits[(size_t)m * Vv + targets[m]];
}

__global__ __launch_bounds__(256) void loss_final(const float* __restrict__ nll,
                                                  float* __restrict__ out) {
  int tid = threadIdx.x;
  float s = 0.f;
  for (int i = tid; i < Mm; i += 256) s += nll[i];
  __shared__ float red[256];
  red[tid] = s;
  __syncthreads();
  for (int k = 128; k > 0; k >>= 1) {
    if (tid < k) red[tid] += red[tid + k];
    __syncthreads();
  }
  if (tid == 0) out[0] = red[0] * (1.f / (float)Mm);
}

// ---------- launcher ----------
extern "C" void kernel_launch(void* const* d_in, const int* in_sizes, int n_in,
                              void* d_out, int out_size, void* d_ws, size_t ws_size,
                              hipStream_t stream) {
  (void)in_sizes; (void)n_in; (void)out_size; (void)ws_size;
  const int* idx      = (const int*)d_in[0];
  const int* targets  = (const int*)d_in[1];
  const float* tok    = (const float*)d_in[2];
  const float* pos    = (const float*)d_in[3];
  const float* wq     = (const float*)d_in[4];
  const float* wk     = (const float*)d_in[5];
  const float* wv     = (const float*)d_in[6];
  const float* wffn   = (const float*)d_in[7];
  const float* bffn   = (const float*)d_in[8];
  const float* wlm    = (const float*)d_in[9];
  float* out = (float*)d_out;

  char* w8 = (char*)d_ws;
  u16* x_bf  = (u16*)(w8);                          // 8 MiB   [4096][1024]
  u16* wqkvT = (u16*)(w8 + ((size_t)8 << 20));      // 6 MiB   [3][16][64][1024]
  u16* qb    = (u16*)(w8 + ((size_t)14 << 20));     // 8 MiB   [2][16][2048][64]
  u16* kb    = (u16*)(w8 + ((size_t)22 << 20));     // 8 MiB
  u16* vTb   = (u16*)(w8 + ((size_t)30 << 20));     // 8 MiB   [2][16][64][2048]
  u16* attnb = (u16*)(w8 + ((size_t)38 << 20));     // 8 MiB   [4096][1024]
  u16* ffnb  = (u16*)(w8 + ((size_t)46 << 20));     // 8 MiB   [4096][1024]
  u16* wffnT = (u16*)(w8 + ((size_t)54 << 20));     // 2 MiB   [1024][1024]
  u16* wlmT  = (u16*)(w8 + ((size_t)56 << 20));     // 62.5MiB [32000][1024]
  float* nllp = (float*)(w8 + ((size_t)119 << 20)); // 16 KiB
  // logsumexp partials [250][4096] float2 = 7.81 MiB, overlays x_bf
  // (x_bf is dead after gemm_bt<2>, which runs before gemm_bt<0>)
  float2* stats = (float2*)(w8);

  embed_kernel<<<2048, 256, 0, stream>>>(idx, tok, pos, x_bf);
  prep_qkv<<<(3 * Hh * Dd * Ee) / 256, 256, 0, stream>>>(wq, wk, wv, wqkvT);
  transpose_f32_bf16<<<dim3(Ee / 64, Ee / 64), 256, 0, stream>>>(wffn, wffnT, Ee, Ee);
  transpose_f32_bf16<<<dim3(Vv / 64, Ee / 64), 256, 0, stream>>>(wlm, wlmT, Ee, Vv);

  gemm_bt<2><<<dim3((3 * Hh * Dd) / 128, Mm / 128), 256, 0, stream>>>(
      x_bf, wqkvT, Mm, 3 * Hh * Dd, Ee, nullptr, nullptr, nullptr, qb, kb, vTb, nullptr);

  attn_kernel<<<dim3(Tt / 64, Hh, Bb), 256, 0, stream>>>(qb, kb, vTb, attnb);

  gemm_bt<1><<<dim3(Ee / 128, Mm / 128), 256, 0, stream>>>(
      attnb, wffnT, Mm, Ee, Ee, nullptr, ffnb, bffn, nullptr, nullptr, nullptr, nullptr);

  gemm_bt<0><<<dim3(Vv / 128, Mm / 128), 256, 0, stream>>>(
      ffnb, wlmT, Mm, Vv, Ee, out, nullptr, nullptr, nullptr, nullptr, nullptr, stats);

  loss_row2<<<Mm, 256, 0, stream>>>(stats, out, targets, nllp);
  loss_final<<<1, 256, 0, stream>>>(nllp, out + (size_t)Mm * Vv);
}